// Round 1
// baseline (40.230 us; speedup 1.0000x reference)
//
#include <hip/hip_runtime.h>
#include <math.h>

#define THREADS 256

// b[j] = -k * ||y_j||^2
__global__ void kde_prep(const float* __restrict__ train, float* __restrict__ b,
                         int N, float negk) {
  int j = blockIdx.x * blockDim.x + threadIdx.x;
  if (j < N) {
    const float4* t = reinterpret_cast<const float4*>(train) + (size_t)j * 2;
    float4 y0 = t[0];
    float4 y1 = t[1];
    float s = y0.x * y0.x + y0.y * y0.y + y0.z * y0.z + y0.w * y0.w +
              y1.x * y1.x + y1.y * y1.y + y1.z * y1.z + y1.w * y1.w;
    b[j] = negk * s;
  }
}

// Each block: one 256-test tile x one train chunk. Per-thread partial sum
// of exp2(a_m + b_j + 2k * dot(x_m, y_j)) over the chunk.
__global__ __launch_bounds__(THREADS) void kde_main(
    const float* __restrict__ test, const float* __restrict__ train,
    const float* __restrict__ b, float* __restrict__ partial,
    int M, int N, int nsplit, int chunk, float negk, float twok) {
  int tile = blockIdx.x / nsplit;
  int split = blockIdx.x - tile * nsplit;
  int m = tile * THREADS + threadIdx.x;
  if (m >= M) return;

  const float4* xp = reinterpret_cast<const float4*>(test) + (size_t)m * 2;
  float4 x0 = xp[0];
  float4 x1 = xp[1];
  float a = negk * (x0.x * x0.x + x0.y * x0.y + x0.z * x0.z + x0.w * x0.w +
                    x1.x * x1.x + x1.y * x1.y + x1.z * x1.z + x1.w * x1.w);

  int j0 = split * chunk;
  int j1 = min(N, j0 + chunk);
  float acc = 0.0f;
#pragma unroll 4
  for (int j = j0; j < j1; ++j) {
    // j is wave-uniform -> these should become scalar loads (s_load_dwordx4)
    const float* y = train + (size_t)j * 8;
    float dot = x0.x * y[0];
    dot = fmaf(x0.y, y[1], dot);
    dot = fmaf(x0.z, y[2], dot);
    dot = fmaf(x0.w, y[3], dot);
    dot = fmaf(x1.x, y[4], dot);
    dot = fmaf(x1.y, y[5], dot);
    dot = fmaf(x1.z, y[6], dot);
    dot = fmaf(x1.w, y[7], dot);
    float arg = fmaf(twok, dot, a + b[j]);
    acc += __builtin_amdgcn_exp2f(arg);
  }
  partial[(size_t)split * M + m] = acc;
}

__global__ void kde_reduce(const float* __restrict__ partial,
                           float* __restrict__ out, int M, int nsplit,
                           float scale) {
  int m = blockIdx.x * blockDim.x + threadIdx.x;
  if (m < M) {
    float s = 0.0f;
    for (int i = 0; i < nsplit; ++i) s += partial[(size_t)i * M + m];
    out[m] = scale * s;
  }
}

extern "C" void kernel_launch(void* const* d_in, const int* in_sizes, int n_in,
                              void* d_out, int out_size, void* d_ws,
                              size_t ws_size, hipStream_t stream) {
  const float* test = (const float*)d_in[0];
  const float* train = (const float*)d_in[1];
  float* out = (float*)d_out;
  int M = in_sizes[0] / 8;
  int N = in_sizes[1] / 8;

  const double var = 0.05 * 0.05;
  const double k = 1.4426950408889634 / (2.0 * var);  // log2(e) / (2 var)
  const float negk = (float)(-k);
  const float twok = (float)(2.0 * k);
  const float coef = (float)(1.0 / sqrt(2.0 * M_PI * var));
  const float scale = coef / (float)N;

  // ws layout: [ b : N floats ][ partial : nsplit*M floats ]
  int nsplit = 32;
  size_t avail = ws_size / sizeof(float);
  while (nsplit > 1 && (size_t)N + (size_t)nsplit * (size_t)M > avail)
    nsplit >>= 1;
  float* b = (float*)d_ws;
  float* partial = b + N;
  int chunk = (N + nsplit - 1) / nsplit;

  kde_prep<<<(N + 255) / 256, 256, 0, stream>>>(train, b, N, negk);
  int ntiles = (M + THREADS - 1) / THREADS;
  kde_main<<<ntiles * nsplit, THREADS, 0, stream>>>(test, train, b, partial, M,
                                                    N, nsplit, chunk, negk,
                                                    twok);
  kde_reduce<<<(M + 255) / 256, 256, 0, stream>>>(partial, out, M, nsplit,
                                                  scale);
}